// Round 2
// baseline (1242.568 us; speedup 1.0000x reference)
//
#include <hip/hip_runtime.h>

#define NE    512
#define DIM   64
#define NROWS 131072            // 32*64*64
#define QELEMS (NROWS * DIM)    // 8388608

// ---- output layout (flat f32, reference return order) ----
#define OFF_Q     0
#define OFF_LOSS  8388608
#define OFF_INDS  8388609
#define OFF_NEMB  8519681       // OFF_INDS + 131072
#define OFF_NCS   8552449       // OFF_NEMB + 32768
#define OFF_NEA   8552961       // OFF_NCS  + 512

// ---- workspace layout (float-unit offsets; some arrays are int) ----
#define WS_EMBT    0            // [512][64] f32 transposed codebook
#define WS_ENORM   32768        // [512] f32 ||e||^2
#define WS_ESUM    33280        // [512][64] f32 segment sums (e-major!)
#define WS_COUNTSF 66048        // [512] f32 counts
#define WS_LOSS    66560        // [1] f32
#define WS_HIST    66561        // [512] int
#define WS_START   67073        // [512] int bucket starts
#define WS_CURS    67585        // [512] int scatter cursors
#define WS_INDS    68097        // [131072] int row -> code
#define WS_SORT    199169       // [131072] int sorted row ids

// ---------------------------------------------------------------------------
// init: build embT + enorm, zero hist + loss.  grid = 132 x 256 (33792 thr)
__global__ __launch_bounds__(256) void k_init(const float* __restrict__ embed,
                                              float* __restrict__ wsf,
                                              int* __restrict__ wsi) {
    int tid = blockIdx.x * 256 + threadIdx.x;
    if (tid < 32768) {
        int e = tid >> 6, d = tid & 63;
        wsf[WS_EMBT + tid] = embed[d * NE + e];          // embT[e][d] = embed[d][e]
    } else if (tid < 33280) {
        int e = tid - 32768;
        float s = 0.f;
        for (int d = 0; d < DIM; ++d) {
            float v = embed[d * NE + e];
            s = fmaf(v, v, s);
        }
        wsf[WS_ENORM + e] = s;
    } else {
        int k = tid - 33280;                             // 0..511
        if (k == 0) wsf[WS_LOSS] = 0.f;
        wsi[WS_HIST + k] = 0;
    }
}

// ---------------------------------------------------------------------------
// argmin: one row per thread; fp32 best-2 scan + fp64 re-rank; LDS histogram.
__global__ __launch_bounds__(256) void k_argmin(const float* __restrict__ in,
                                                const float* __restrict__ wsf,
                                                int* __restrict__ wsi,
                                                float* __restrict__ inds_out) {
    const float* __restrict__ embT  = wsf + WS_EMBT;
    const float* __restrict__ enorm = wsf + WS_ENORM;
    __shared__ int h[NE];
    for (int i = threadIdx.x; i < NE; i += 256) h[i] = 0;
    __syncthreads();

    int row = blockIdx.x * 256 + threadIdx.x;

    float xv[DIM];
    const float4* xp = reinterpret_cast<const float4*>(in + (size_t)row * DIM);
#pragma unroll
    for (int i = 0; i < DIM / 4; ++i) {
        float4 v = xp[i];
        xv[4*i+0] = v.x; xv[4*i+1] = v.y; xv[4*i+2] = v.z; xv[4*i+3] = v.w;
    }

    float b0 = 3.4e38f, b1 = 3.4e38f;
    int   i0 = 0,       i1 = 0;
    for (int e = 0; e < NE; ++e) {
        const float* __restrict__ ec = embT + e * DIM;   // wave-uniform -> s_load
        float a0 = 0.f, a1 = 0.f, a2 = 0.f, a3 = 0.f;
#pragma unroll
        for (int d = 0; d < DIM; d += 4) {
            a0 = fmaf(xv[d+0], ec[d+0], a0);
            a1 = fmaf(xv[d+1], ec[d+1], a1);
            a2 = fmaf(xv[d+2], ec[d+2], a2);
            a3 = fmaf(xv[d+3], ec[d+3], a3);
        }
        float dist = enorm[e] - 2.0f * ((a0 + a1) + (a2 + a3));
        bool better0 = dist < b0;
        bool better1 = dist < b1;
        b1 = better0 ? b0 : (better1 ? dist : b1);
        i1 = better0 ? i0 : (better1 ? e    : i1);
        b0 = better0 ? dist : b0;
        i0 = better0 ? e    : i0;
    }

    // fp64 re-rank of the two candidates (||x||^2 cancels in the comparison)
    const float* __restrict__ e0 = embT + i0 * DIM;
    const float* __restrict__ e1 = embT + i1 * DIM;
    double s0 = 0.0, s1 = 0.0;
#pragma unroll
    for (int d = 0; d < DIM; ++d) {
        double xd = (double)xv[d];
        double a = (double)e0[d]; s0 += a * (a - 2.0 * xd);
        double b = (double)e1[d]; s1 += b * (b - 2.0 * xd);
    }
    int best = (s1 < s0 || (s1 == s0 && i1 < i0)) ? i1 : i0;
    inds_out[row] = (float)best;
    wsi[WS_INDS + row] = best;

    atomicAdd(&h[best], 1);
    __syncthreads();
    for (int i = threadIdx.x; i < NE; i += 256)
        if (h[i]) atomicAdd(&wsi[WS_HIST + i], h[i]);
}

// ---------------------------------------------------------------------------
// prefix: exclusive scan of hist -> starts & cursors; counts as float. 1 block.
__global__ __launch_bounds__(512) void k_prefix(int* __restrict__ wsi,
                                                float* __restrict__ wsf) {
    __shared__ int s[NE];
    int t = threadIdx.x;
    int v = wsi[WS_HIST + t];
    s[t] = v;
    __syncthreads();
    for (int off = 1; off < NE; off <<= 1) {
        int a = (t >= off) ? s[t - off] : 0;
        __syncthreads();
        s[t] += a;
        __syncthreads();
    }
    int start = s[t] - v;                                // exclusive
    wsi[WS_START + t] = start;
    wsi[WS_CURS + t]  = start;
    wsf[WS_COUNTSF + t] = (float)v;
}

// ---------------------------------------------------------------------------
// scatter: counting-sort row ids by code. 131072 atomics over 512 cursors.
__global__ __launch_bounds__(256) void k_scatter(int* __restrict__ wsi) {
    int row = blockIdx.x * 256 + threadIdx.x;
    int ind = wsi[WS_INDS + row];
    int pos = atomicAdd(&wsi[WS_CURS + ind], 1);
    wsi[WS_SORT + pos] = row;
}

// ---------------------------------------------------------------------------
// sum: one block per code; sum bucket rows. No atomics. esum[e][d].
__global__ __launch_bounds__(256) void k_sum(const float* __restrict__ in,
                                             const int* __restrict__ wsi,
                                             float* __restrict__ wsf) {
    int e = blockIdx.x;
    int start = wsi[WS_START + e];
    int cnt   = wsi[WS_HIST + e];
    int wv = threadIdx.x >> 6, lane = threadIdx.x & 63;
    float acc = 0.f;
    for (int i = wv; i < cnt; i += 4) {
        int row = wsi[WS_SORT + start + i];              // wave-uniform
        acc += in[(size_t)row * DIM + lane];             // coalesced 256B
    }
    __shared__ float part[4][DIM];
    part[wv][lane] = acc;
    __syncthreads();
    if (threadIdx.x < DIM) {
        int d = threadIdx.x;
        wsf[WS_ESUM + e * DIM + d] =
            part[0][d] + part[1][d] + part[2][d] + part[3][d];
    }
}

// ---------------------------------------------------------------------------
// quant: gather quantized rows (float4/lane) + loss. grid = 8192 x 256.
__global__ __launch_bounds__(256) void k_quant(const float* __restrict__ in,
                                               const float* __restrict__ wsf,
                                               const int* __restrict__ wsi,
                                               float* __restrict__ wsmut,
                                               float* __restrict__ qout) {
    const float4* __restrict__ in4   = reinterpret_cast<const float4*>(in);
    const float4* __restrict__ embT4 = reinterpret_cast<const float4*>(wsf + WS_EMBT);
    float4* __restrict__ q4          = reinterpret_cast<float4*>(qout);

    int gtid = blockIdx.x * 256 + threadIdx.x;           // 0 .. 2097151
    int row  = gtid >> 4;
    int c4   = gtid & 15;
    int ind  = wsi[WS_INDS + row];
    float4 x = in4[gtid];
    float4 q = embT4[ind * 16 + c4];
    q4[gtid] = q;
    float dx = q.x - x.x, dy = q.y - x.y, dz = q.z - x.z, dw = q.w - x.w;
    float lsum = dx*dx + dy*dy + dz*dz + dw*dw;

    for (int off = 32; off; off >>= 1) lsum += __shfl_down(lsum, off, 64);
    __shared__ float red[4];
    int wv = threadIdx.x >> 6, lane = threadIdx.x & 63;
    if (lane == 0) red[wv] = lsum;
    __syncthreads();
    if (threadIdx.x == 0)
        atomicAdd(&wsmut[WS_LOSS], red[0] + red[1] + red[2] + red[3]);
}

// ---------------------------------------------------------------------------
// finalize: EMA buffers + normalized codebook + loss scale. One block.
__global__ __launch_bounds__(512) void k_final(const float* __restrict__ wsf,
                                               const float* __restrict__ cs_in,
                                               const float* __restrict__ eavg_in,
                                               float* __restrict__ out) {
    __shared__ float sred[512];
    int t = threadIdx.x;
    float c = 0.99f * cs_in[t] + 0.01f * wsf[WS_COUNTSF + t];
    out[OFF_NCS + t] = c;
    sred[t] = c;
    __syncthreads();
    for (int s = 256; s; s >>= 1) {
        if (t < s) sred[t] += sred[t + s];
        __syncthreads();
    }
    float n = sred[0];
    float csv = (c + 1e-5f) / (n + NE * 1e-5f) * n;
    for (int i = t; i < 32768; i += 512) {               // i & 511 == t, d = i>>9
        float nea = 0.99f * eavg_in[i] + 0.01f * wsf[WS_ESUM + t * DIM + (i >> 9)];
        out[OFF_NEA + i]  = nea;
        out[OFF_NEMB + i] = nea / csv;
    }
    if (t == 0) out[OFF_LOSS] = wsf[WS_LOSS] * (1.25f / 8388608.0f);
}

// ---------------------------------------------------------------------------
extern "C" void kernel_launch(void* const* d_in, const int* in_sizes, int n_in,
                              void* d_out, int out_size, void* d_ws, size_t ws_size,
                              hipStream_t stream) {
    const float* in    = (const float*)d_in[0];
    const float* embed = (const float*)d_in[1];
    const float* cs    = (const float*)d_in[2];
    const float* eavg  = (const float*)d_in[3];
    float* out = (float*)d_out;
    float* wsf = (float*)d_ws;
    int*   wsi = (int*)d_ws;

    k_init   <<<132, 256, 0, stream>>>(embed, wsf, wsi);
    k_argmin <<<NROWS / 256, 256, 0, stream>>>(in, wsf, wsi, out + OFF_INDS);
    k_prefix <<<1, 512, 0, stream>>>(wsi, wsf);
    k_scatter<<<NROWS / 256, 256, 0, stream>>>(wsi);
    k_sum    <<<NE, 256, 0, stream>>>(in, wsi, wsf);
    k_quant  <<<QELEMS / 4 / 256, 256, 0, stream>>>(in, wsf, wsi, wsf, out + OFF_Q);
    k_final  <<<1, 512, 0, stream>>>(wsf, cs, eavg, out);
}

// Round 3
// 476.011 us; speedup vs baseline: 2.6104x; 2.6104x over previous
//
#include <hip/hip_runtime.h>

#define NE    512
#define DIM   64
#define NROWS 131072            // 32*64*64
#define QELEMS (NROWS * DIM)    // 8388608

// ---- output layout (flat f32, reference return order) ----
#define OFF_Q     0
#define OFF_LOSS  8388608
#define OFF_INDS  8388609
#define OFF_NEMB  8519681       // OFF_INDS + 131072
#define OFF_NCS   8552449       // OFF_NEMB + 32768
#define OFF_NEA   8552961       // OFF_NCS  + 512

// ---- workspace layout (float-unit offsets; some arrays are int) ----
#define WS_EMBT    0            // [512][64] f32 transposed codebook
#define WS_ENORM   32768        // [512] f32 ||e||^2
#define WS_ESUM    33280        // [512][64] f32 segment sums (e-major, atomic)
#define WS_COUNTSF 66048        // [512] f32 counts
#define WS_LOSS    66560        // [1] f32
#define WS_HIST    66561        // [512] int
#define WS_START   67073        // [512] int bucket starts
#define WS_CURS    67585        // [512] int scatter cursors
#define WS_INDS    68097        // [131072] int row -> code
#define WS_SORT    199169       // [131072] int sorted row ids

// ---------------------------------------------------------------------------
// init: build embT + enorm, zero esum + hist + loss. grid = 260 x 256.
__global__ __launch_bounds__(256) void k_init(const float* __restrict__ embed,
                                              float* __restrict__ wsf,
                                              int* __restrict__ wsi) {
    int tid = blockIdx.x * 256 + threadIdx.x;
    if (tid < 32768) {
        int e = tid >> 6, d = tid & 63;
        wsf[WS_EMBT + tid] = embed[d * NE + e];          // embT[e][d] = embed[d][e]
    } else if (tid < 33280) {
        int e = tid - 32768;
        float s = 0.f;
        for (int d = 0; d < DIM; ++d) {
            float v = embed[d * NE + e];
            s = fmaf(v, v, s);
        }
        wsf[WS_ENORM + e] = s;
    } else if (tid < 66048) {
        wsf[tid] = 0.f;                                  // WS_ESUM range exactly
    } else if (tid < 66560) {
        wsi[WS_HIST + (tid - 66048)] = 0;
        if (tid == 66048) wsf[WS_LOSS] = 0.f;
    }
}

// ---------------------------------------------------------------------------
// argmin: one row per thread; fp32 best-2 scan + fp64 re-rank; LDS histogram.
__global__ __launch_bounds__(256) void k_argmin(const float* __restrict__ in,
                                                const float* __restrict__ wsf,
                                                int* __restrict__ wsi,
                                                float* __restrict__ inds_out) {
    const float* __restrict__ embT  = wsf + WS_EMBT;
    const float* __restrict__ enorm = wsf + WS_ENORM;
    __shared__ int h[NE];
    for (int i = threadIdx.x; i < NE; i += 256) h[i] = 0;
    __syncthreads();

    int row = blockIdx.x * 256 + threadIdx.x;

    float xv[DIM];
    const float4* xp = reinterpret_cast<const float4*>(in + (size_t)row * DIM);
#pragma unroll
    for (int i = 0; i < DIM / 4; ++i) {
        float4 v = xp[i];
        xv[4*i+0] = v.x; xv[4*i+1] = v.y; xv[4*i+2] = v.z; xv[4*i+3] = v.w;
    }

    float b0 = 3.4e38f, b1 = 3.4e38f;
    int   i0 = 0,       i1 = 0;
    for (int e = 0; e < NE; ++e) {
        const float* __restrict__ ec = embT + e * DIM;   // wave-uniform -> s_load
        float a0 = 0.f, a1 = 0.f, a2 = 0.f, a3 = 0.f;
#pragma unroll
        for (int d = 0; d < DIM; d += 4) {
            a0 = fmaf(xv[d+0], ec[d+0], a0);
            a1 = fmaf(xv[d+1], ec[d+1], a1);
            a2 = fmaf(xv[d+2], ec[d+2], a2);
            a3 = fmaf(xv[d+3], ec[d+3], a3);
        }
        float dist = enorm[e] - 2.0f * ((a0 + a1) + (a2 + a3));
        bool better0 = dist < b0;
        bool better1 = dist < b1;
        b1 = better0 ? b0 : (better1 ? dist : b1);
        i1 = better0 ? i0 : (better1 ? e    : i1);
        b0 = better0 ? dist : b0;
        i0 = better0 ? e    : i0;
    }

    // fp64 re-rank of the two candidates (||x||^2 cancels in the comparison)
    const float* __restrict__ e0 = embT + i0 * DIM;
    const float* __restrict__ e1 = embT + i1 * DIM;
    double s0 = 0.0, s1 = 0.0;
#pragma unroll
    for (int d = 0; d < DIM; ++d) {
        double xd = (double)xv[d];
        double a = (double)e0[d]; s0 += a * (a - 2.0 * xd);
        double b = (double)e1[d]; s1 += b * (b - 2.0 * xd);
    }
    int best = (s1 < s0 || (s1 == s0 && i1 < i0)) ? i1 : i0;
    inds_out[row] = (float)best;
    wsi[WS_INDS + row] = best;

    atomicAdd(&h[best], 1);
    __syncthreads();
    for (int i = threadIdx.x; i < NE; i += 256)
        if (h[i]) atomicAdd(&wsi[WS_HIST + i], h[i]);
}

// ---------------------------------------------------------------------------
// prefix: exclusive scan of hist -> starts & cursors; counts as float. 1 block.
__global__ __launch_bounds__(512) void k_prefix(int* __restrict__ wsi,
                                                float* __restrict__ wsf) {
    __shared__ int s[NE];
    int t = threadIdx.x;
    int v = wsi[WS_HIST + t];
    s[t] = v;
    __syncthreads();
    for (int off = 1; off < NE; off <<= 1) {
        int a = (t >= off) ? s[t - off] : 0;
        __syncthreads();
        s[t] += a;
        __syncthreads();
    }
    int start = s[t] - v;                                // exclusive
    wsi[WS_START + t] = start;
    wsi[WS_CURS + t]  = start;
    wsf[WS_COUNTSF + t] = (float)v;
}

// ---------------------------------------------------------------------------
// scatter: counting-sort row ids by code. 131072 atomics over 512 cursors.
__global__ __launch_bounds__(256) void k_scatter(int* __restrict__ wsi) {
    int row = blockIdx.x * 256 + threadIdx.x;
    int ind = wsi[WS_INDS + row];
    int pos = atomicAdd(&wsi[WS_CURS + ind], 1);
    wsi[WS_SORT + pos] = row;
}

// ---------------------------------------------------------------------------
// sum: skew-immune. Each wave owns 32 contiguous SORTED positions; rowids and
// codes preloaded coalesced, broadcast per-j via shfl; flush esum on (rare,
// wave-uniform) code change. grid = 1024 x 256 (4096 waves x 32 rows).
__global__ __launch_bounds__(256) void k_sum(const float* __restrict__ in,
                                             const int* __restrict__ wsi,
                                             float* __restrict__ wsf) {
    float* __restrict__ esum = wsf + WS_ESUM;
    int wv = threadIdx.x >> 6, lane = threadIdx.x & 63;
    int base = (blockIdx.x * 4 + wv) * 32;               // first sorted pos
    int rid = 0, cod = 0;
    if (lane < 32) {
        rid = wsi[WS_SORT + base + lane];
        cod = wsi[WS_INDS + rid];
    }
    float acc = 0.f;
    int cur = __shfl(cod, 0, 64);
#pragma unroll 8
    for (int j = 0; j < 32; ++j) {
        int cj = __shfl(cod, j, 64);
        int rj = __shfl(rid, j, 64);
        if (cj != cur) {                                 // wave-uniform branch
            atomicAdd(&esum[cur * DIM + lane], acc);
            acc = 0.f;
            cur = cj;
        }
        acc += in[(size_t)rj * DIM + lane];              // coalesced 256B
    }
    atomicAdd(&esum[cur * DIM + lane], acc);
}

// ---------------------------------------------------------------------------
// quant: gather quantized rows (float4/lane) + loss. grid = 8192 x 256.
__global__ __launch_bounds__(256) void k_quant(const float* __restrict__ in,
                                               const float* __restrict__ wsf,
                                               const int* __restrict__ wsi,
                                               float* __restrict__ wsmut,
                                               float* __restrict__ qout) {
    const float4* __restrict__ in4   = reinterpret_cast<const float4*>(in);
    const float4* __restrict__ embT4 = reinterpret_cast<const float4*>(wsf + WS_EMBT);
    float4* __restrict__ q4          = reinterpret_cast<float4*>(qout);

    int gtid = blockIdx.x * 256 + threadIdx.x;           // 0 .. 2097151
    int row  = gtid >> 4;
    int c4   = gtid & 15;
    int ind  = wsi[WS_INDS + row];
    float4 x = in4[gtid];
    float4 q = embT4[ind * 16 + c4];
    q4[gtid] = q;
    float dx = q.x - x.x, dy = q.y - x.y, dz = q.z - x.z, dw = q.w - x.w;
    float lsum = dx*dx + dy*dy + dz*dz + dw*dw;

    for (int off = 32; off; off >>= 1) lsum += __shfl_down(lsum, off, 64);
    __shared__ float red[4];
    int wv = threadIdx.x >> 6, lane = threadIdx.x & 63;
    if (lane == 0) red[wv] = lsum;
    __syncthreads();
    if (threadIdx.x == 0)
        atomicAdd(&wsmut[WS_LOSS], red[0] + red[1] + red[2] + red[3]);
}

// ---------------------------------------------------------------------------
// finalize: EMA buffers + normalized codebook + loss scale. One block.
__global__ __launch_bounds__(512) void k_final(const float* __restrict__ wsf,
                                               const float* __restrict__ cs_in,
                                               const float* __restrict__ eavg_in,
                                               float* __restrict__ out) {
    __shared__ float sred[512];
    int t = threadIdx.x;
    float c = 0.99f * cs_in[t] + 0.01f * wsf[WS_COUNTSF + t];
    out[OFF_NCS + t] = c;
    sred[t] = c;
    __syncthreads();
    for (int s = 256; s; s >>= 1) {
        if (t < s) sred[t] += sred[t + s];
        __syncthreads();
    }
    float n = sred[0];
    float csv = (c + 1e-5f) / (n + NE * 1e-5f) * n;
    for (int i = t; i < 32768; i += 512) {               // i & 511 == t, d = i>>9
        float nea = 0.99f * eavg_in[i] + 0.01f * wsf[WS_ESUM + t * DIM + (i >> 9)];
        out[OFF_NEA + i]  = nea;
        out[OFF_NEMB + i] = nea / csv;
    }
    if (t == 0) out[OFF_LOSS] = wsf[WS_LOSS] * (1.25f / 8388608.0f);
}

// ---------------------------------------------------------------------------
extern "C" void kernel_launch(void* const* d_in, const int* in_sizes, int n_in,
                              void* d_out, int out_size, void* d_ws, size_t ws_size,
                              hipStream_t stream) {
    const float* in    = (const float*)d_in[0];
    const float* embed = (const float*)d_in[1];
    const float* cs    = (const float*)d_in[2];
    const float* eavg  = (const float*)d_in[3];
    float* out = (float*)d_out;
    float* wsf = (float*)d_ws;
    int*   wsi = (int*)d_ws;

    k_init   <<<260, 256, 0, stream>>>(embed, wsf, wsi);
    k_argmin <<<NROWS / 256, 256, 0, stream>>>(in, wsf, wsi, out + OFF_INDS);
    k_prefix <<<1, 512, 0, stream>>>(wsi, wsf);
    k_scatter<<<NROWS / 256, 256, 0, stream>>>(wsi);
    k_sum    <<<1024, 256, 0, stream>>>(in, wsi, wsf);
    k_quant  <<<QELEMS / 4 / 256, 256, 0, stream>>>(in, wsf, wsi, wsf, out + OFF_Q);
    k_final  <<<1, 512, 0, stream>>>(wsf, cs, eavg, out);
}

// Round 4
// 102.475 us; speedup vs baseline: 12.1255x; 4.6451x over previous
//
#include <hip/hip_runtime.h>

#define NE    512
#define DIM   64
#define NROWS 131072            // 32*64*64
#define QELEMS (NROWS * DIM)    // 8388608

// ---- output layout (flat f32, reference return order) ----
#define OFF_Q     0
#define OFF_LOSS  8388608
#define OFF_INDS  8388609
#define OFF_NEMB  8519681       // OFF_INDS + 131072
#define OFF_NCS   8552449       // OFF_NEMB + 32768
#define OFF_NEA   8552961       // OFF_NCS  + 512

// ---- workspace layout (float-unit offsets; some regions are int/ushort) ----
#define WS_EMBT    0            // [512][64] f32 transposed codebook (e-major)
#define WS_ENORM   32768        // [512] f32 ||e||^2
#define WS_ESUM    33280        // [512][64] f32 segment sums (e-major, atomic)
#define WS_COUNTSF 66048        // [512] f32 counts
#define WS_LOSS    66560        // [1] f32
#define WS_HIST    66561        // [512] int per-code totals
#define WS_START   67073        // [512] int bucket starts
#define WS_INDS    68097        // [131072] int row -> code
#define WS_SORT    199169       // [131072] int sorted row ids
#define WS_FRAG_F  199172       // [65536] ushort bf16 frags (hi then lo) - 16B aligned,
                                //   OVERLAPS WS_SORT (frags dead before scatter writes)
#define WS_HIST2   330241       // [512][256] int per-(code,block) hist -> scanned offsets

typedef __attribute__((ext_vector_type(8))) short short8;
typedef __attribute__((ext_vector_type(4))) float float4v;

__device__ inline unsigned short bf16_rne(float v) {
    unsigned u = __float_as_uint(v);
    u += 0x7fff + ((u >> 16) & 1);
    return (unsigned short)(u >> 16);
}

__device__ inline void upd2(float& B0, int& I0, float& B1, int& I1, float d, int n) {
    bool c0 = d < B0;
    bool c1 = d < B1;
    B1 = c0 ? B0 : (c1 ? d : B1);
    I1 = c0 ? I0 : (c1 ? n : I1);
    B0 = c0 ? d  : B0;
    I0 = c0 ? n  : I0;
}

// ---------------------------------------------------------------------------
// init: embT + enorm + zero esum/loss + build pre-swizzled bf16 hi/lo frags.
// grid = 386 x 256 = 98816 threads exactly.
__global__ __launch_bounds__(256) void k_init(const float* __restrict__ embed,
                                              float* __restrict__ wsf,
                                              int* __restrict__ wsi) {
    int tid = blockIdx.x * 256 + threadIdx.x;
    if (tid < 32768) {
        int e = tid >> 6, d = tid & 63;
        wsf[WS_EMBT + tid] = embed[d * NE + e];          // embT[e][d]
    } else if (tid < 33280) {
        int e = tid - 32768;
        float s = 0.f;
        for (int d = 0; d < DIM; ++d) {
            float v = embed[d * NE + e];
            s = fmaf(v, v, s);
        }
        wsf[WS_ENORM + e] = s;
        if (e == 0) wsf[WS_LOSS] = 0.f;
    } else if (tid < 66048) {
        wsf[tid] = 0.f;                                  // zero WS_ESUM exactly
    } else {
        // frag build: ft in [0,32768): value embed[k][n] split to bf16 hi/lo.
        // layout: [t(32)][kt(2)][lane(64)][j(8)]; k = kt*32 + 8*(lane>>4) + j,
        //         n = 16*t + (lane&15)
        int ft = tid - 66048;
        int j  = ft & 7;
        int l  = (ft >> 3) & 63;
        int kt = (ft >> 9) & 1;
        int t  = ft >> 10;
        int k  = kt * 32 + 8 * (l >> 4) + j;
        int n  = 16 * t + (l & 15);
        float v = embed[k * NE + n];
        unsigned short hi = bf16_rne(v);
        float fhi = __uint_as_float((unsigned)hi << 16);
        unsigned short lo = bf16_rne(v - fhi);
        unsigned short* fh = (unsigned short*)(wsf + WS_FRAG_F);
        fh[ft]         = hi;
        fh[32768 + ft] = lo;
    }
}

// ---------------------------------------------------------------------------
// argmin via split-bf16 MFMA + fused fp64 re-rank + quantized gather + loss +
// per-block histogram. block = 1024 thr (16 waves x 32 rows), grid = 256.
// dynamic LDS: 64KB hi frags + 64KB lo frags + 2KB enorm + 2KB hist + 64B red.
__global__ __launch_bounds__(1024, 4) void k_argmin(const float* __restrict__ in,
                                                    float* __restrict__ wsf,
                                                    int* __restrict__ wsi,
                                                    float* __restrict__ inds_out,
                                                    float* __restrict__ qout) {
    extern __shared__ char smem[];
    short* lhi = (short*)smem;                 // 32768 shorts
    short* llo = lhi + 32768;                  // 32768 shorts
    float* len = (float*)(llo + 32768);        // 512 f32
    int*   lh  = (int*)(len + 512);            // 512 int
    float* lwr = (float*)(lh + 512);           // 16 f32

    // stage frags (128KB) + enorm; zero hist
    {
        const int4* src = (const int4*)(wsf + WS_FRAG_F);
        int4* dst = (int4*)lhi;
        for (int i = threadIdx.x; i < 8192; i += 1024) dst[i] = src[i];
        if (threadIdx.x < 512) {
            len[threadIdx.x] = wsf[WS_ENORM + threadIdx.x];
            lh[threadIdx.x] = 0;
        }
    }
    __syncthreads();

    const int w = threadIdx.x >> 6, l = threadIdx.x & 63;
    const int g = l >> 4, c = l & 15;
    const int rowbase = blockIdx.x * 512 + w * 32;

    // A fragments: rows (l&15), k-slots 8g..8g+7 per ktile, split hi/lo
    short8 ahi[2][2], alo[2][2];
#pragma unroll
    for (int mt = 0; mt < 2; ++mt) {
        const float* xr = in + (size_t)(rowbase + mt * 16 + c) * DIM;
#pragma unroll
        for (int kt = 0; kt < 2; ++kt) {
            float4v x0 = *(const float4v*)(xr + kt * 32 + 8 * g);
            float4v x1 = *(const float4v*)(xr + kt * 32 + 8 * g + 4);
            float a[8] = {x0[0], x0[1], x0[2], x0[3], x1[0], x1[1], x1[2], x1[3]};
            short8 h, lo8;
#pragma unroll
            for (int j = 0; j < 8; ++j) {
                unsigned short hb = bf16_rne(a[j]);
                float fhi = __uint_as_float((unsigned)hb << 16);
                h[j]   = (short)hb;
                lo8[j] = (short)bf16_rne(a[j] - fhi);
            }
            ahi[mt][kt] = h;
            alo[mt][kt] = lo8;
        }
    }

    float b0v[2][4], b1v[2][4];
    int   b0i[2][4], b1i[2][4];
#pragma unroll
    for (int mt = 0; mt < 2; ++mt)
#pragma unroll
        for (int j = 0; j < 4; ++j) {
            b0v[mt][j] = 3.4e38f; b1v[mt][j] = 3.4e38f;
            b0i[mt][j] = 0;       b1i[mt][j] = 0;
        }

    for (int t = 0; t < 32; ++t) {
        short8 bh0 = *(const short8*)(lhi + (t * 2 + 0) * 512 + l * 8);
        short8 bh1 = *(const short8*)(lhi + (t * 2 + 1) * 512 + l * 8);
        short8 bl0 = *(const short8*)(llo + (t * 2 + 0) * 512 + l * 8);
        short8 bl1 = *(const short8*)(llo + (t * 2 + 1) * 512 + l * 8);
        float4v acc0 = {0.f, 0.f, 0.f, 0.f};
        float4v acc1 = {0.f, 0.f, 0.f, 0.f};
        acc0 = __builtin_amdgcn_mfma_f32_16x16x32_bf16(ahi[0][0], bh0, acc0, 0, 0, 0);
        acc0 = __builtin_amdgcn_mfma_f32_16x16x32_bf16(ahi[0][1], bh1, acc0, 0, 0, 0);
        acc0 = __builtin_amdgcn_mfma_f32_16x16x32_bf16(alo[0][0], bh0, acc0, 0, 0, 0);
        acc0 = __builtin_amdgcn_mfma_f32_16x16x32_bf16(alo[0][1], bh1, acc0, 0, 0, 0);
        acc0 = __builtin_amdgcn_mfma_f32_16x16x32_bf16(ahi[0][0], bl0, acc0, 0, 0, 0);
        acc0 = __builtin_amdgcn_mfma_f32_16x16x32_bf16(ahi[0][1], bl1, acc0, 0, 0, 0);
        acc1 = __builtin_amdgcn_mfma_f32_16x16x32_bf16(ahi[1][0], bh0, acc1, 0, 0, 0);
        acc1 = __builtin_amdgcn_mfma_f32_16x16x32_bf16(ahi[1][1], bh1, acc1, 0, 0, 0);
        acc1 = __builtin_amdgcn_mfma_f32_16x16x32_bf16(alo[1][0], bh0, acc1, 0, 0, 0);
        acc1 = __builtin_amdgcn_mfma_f32_16x16x32_bf16(alo[1][1], bh1, acc1, 0, 0, 0);
        acc1 = __builtin_amdgcn_mfma_f32_16x16x32_bf16(ahi[1][0], bl0, acc1, 0, 0, 0);
        acc1 = __builtin_amdgcn_mfma_f32_16x16x32_bf16(ahi[1][1], bl1, acc1, 0, 0, 0);

        int n = t * 16 + c;
        float en = len[n];
#pragma unroll
        for (int j = 0; j < 4; ++j) {
            upd2(b0v[0][j], b0i[0][j], b1v[0][j], b1i[0][j], en - 2.f * acc0[j], n);
            upd2(b0v[1][j], b0i[1][j], b1v[1][j], b1i[1][j], en - 2.f * acc1[j], n);
        }
    }

    // per-slot: cross-lane best-2 merge, fp64 re-rank, quantize+loss, hist
    float lsum = 0.f;
#pragma unroll
    for (int mt = 0; mt < 2; ++mt)
#pragma unroll
        for (int j = 0; j < 4; ++j) {
            float B0 = b0v[mt][j], B1 = b1v[mt][j];
            int   I0 = b0i[mt][j], I1 = b1i[mt][j];
#pragma unroll
            for (int m = 1; m < 16; m <<= 1) {
                float o0 = __shfl_xor(B0, m, 64);
                int  oi0 = __shfl_xor(I0, m, 64);
                float o1 = __shfl_xor(B1, m, 64);
                int  oi1 = __shfl_xor(I1, m, 64);
                upd2(B0, I0, B1, I1, o0, oi0);
                upd2(B0, I0, B1, I1, o1, oi1);
            }
            int row = rowbase + mt * 16 + 4 * g + j;     // C/D row = (l>>4)*4 + reg
            float4v x4 = *(const float4v*)(in + (size_t)row * DIM + 4 * c);
            float4v e0 = *(const float4v*)(wsf + WS_EMBT + I0 * DIM + 4 * c);
            float4v e1 = *(const float4v*)(wsf + WS_EMBT + I1 * DIM + 4 * c);
            double s0 = 0.0, s1 = 0.0;
#pragma unroll
            for (int q = 0; q < 4; ++q) {
                double xd = (double)x4[q];
                double a = (double)e0[q]; s0 += a * (a - 2.0 * xd);
                double b = (double)e1[q]; s1 += b * (b - 2.0 * xd);
            }
#pragma unroll
            for (int m = 1; m < 16; m <<= 1) {
                s0 += __shfl_xor(s0, m, 64);
                s1 += __shfl_xor(s1, m, 64);
            }
            bool take1 = (s1 < s0) || (s1 == s0 && I1 < I0);
            int best = take1 ? I1 : I0;
            float4v qv = take1 ? e1 : e0;
            *(float4v*)(qout + (size_t)row * DIM + 4 * c) = qv;
            float4v df = qv - x4;
            lsum += df[0] * df[0] + df[1] * df[1] + df[2] * df[2] + df[3] * df[3];
            if (c == 0) {
                inds_out[row] = (float)best;
                wsi[WS_INDS + row] = best;
                atomicAdd(&lh[best], 1);
            }
        }

    // loss: wave reduce -> LDS -> one global atomic per block
    for (int off = 32; off; off >>= 1) lsum += __shfl_down(lsum, off, 64);
    if (l == 0) lwr[w] = lsum;
    __syncthreads();
    if (threadIdx.x == 0) {
        float s = 0.f;
        for (int i = 0; i < 16; ++i) s += lwr[i];
        atomicAdd(&wsf[WS_LOSS], s);
    }
    // export per-block histogram: hist2[code][block]
    if (threadIdx.x < 512)
        wsi[WS_HIST2 + threadIdx.x * 256 + blockIdx.x] = lh[threadIdx.x];
}

// ---------------------------------------------------------------------------
// scan1: per-code exclusive scan over 256 blocks; totals -> HIST + COUNTSF.
__global__ __launch_bounds__(256) void k_scan1(int* __restrict__ wsi,
                                               float* __restrict__ wsf) {
    __shared__ int s[256];
    int e = blockIdx.x, t = threadIdx.x;
    int v = wsi[WS_HIST2 + e * 256 + t];
    s[t] = v;
    __syncthreads();
    for (int off = 1; off < 256; off <<= 1) {
        int a = (t >= off) ? s[t - off] : 0;
        __syncthreads();
        s[t] += a;
        __syncthreads();
    }
    wsi[WS_HIST2 + e * 256 + t] = s[t] - v;              // exclusive over blocks
    if (t == 255) {
        wsi[WS_HIST + e] = s[255];
        wsf[WS_COUNTSF + e] = (float)s[255];
    }
}

// ---------------------------------------------------------------------------
// scan2: exclusive scan of per-code totals -> bucket starts. 1 block.
__global__ __launch_bounds__(512) void k_scan2(int* __restrict__ wsi) {
    __shared__ int s[NE];
    int t = threadIdx.x;
    int v = wsi[WS_HIST + t];
    s[t] = v;
    __syncthreads();
    for (int off = 1; off < NE; off <<= 1) {
        int a = (t >= off) ? s[t - off] : 0;
        __syncthreads();
        s[t] += a;
        __syncthreads();
    }
    wsi[WS_START + t] = s[t] - v;
}

// ---------------------------------------------------------------------------
// scatter: atomic-free globally; LDS local rank + scanned (code,block) offset.
// grid = 256 blocks x 512 rows (matches argmin block decomposition).
__global__ __launch_bounds__(512) void k_scatter(int* __restrict__ wsi) {
    __shared__ int lc[NE];
    int b = blockIdx.x, t = threadIdx.x;
    lc[t] = 0;
    __syncthreads();
    int row = b * 512 + t;
    int ind = wsi[WS_INDS + row];
    int lr = atomicAdd(&lc[ind], 1);
    int pos = wsi[WS_START + ind] + wsi[WS_HIST2 + ind * 256 + b] + lr;
    wsi[WS_SORT + pos] = row;
}

// ---------------------------------------------------------------------------
// sum: skew-immune; wave owns 32 contiguous sorted positions, shfl broadcast,
// flush on (wave-uniform) code change. grid = 1024 x 256.
__global__ __launch_bounds__(256) void k_sum(const float* __restrict__ in,
                                             const int* __restrict__ wsi,
                                             float* __restrict__ wsf) {
    float* __restrict__ esum = wsf + WS_ESUM;
    int wv = threadIdx.x >> 6, lane = threadIdx.x & 63;
    int base = (blockIdx.x * 4 + wv) * 32;
    int rid = 0, cod = 0;
    if (lane < 32) {
        rid = wsi[WS_SORT + base + lane];
        cod = wsi[WS_INDS + rid];
    }
    float acc = 0.f;
    int cur = __shfl(cod, 0, 64);
#pragma unroll 8
    for (int j = 0; j < 32; ++j) {
        int cj = __shfl(cod, j, 64);
        int rj = __shfl(rid, j, 64);
        if (cj != cur) {
            atomicAdd(&esum[cur * DIM + lane], acc);
            acc = 0.f;
            cur = cj;
        }
        acc += in[(size_t)rj * DIM + lane];
    }
    atomicAdd(&esum[cur * DIM + lane], acc);
}

// ---------------------------------------------------------------------------
// finalize: EMA buffers + normalized codebook + loss scale. One block.
__global__ __launch_bounds__(512) void k_final(const float* __restrict__ wsf,
                                               const float* __restrict__ cs_in,
                                               const float* __restrict__ eavg_in,
                                               float* __restrict__ out) {
    __shared__ float sred[512];
    int t = threadIdx.x;
    float c = 0.99f * cs_in[t] + 0.01f * wsf[WS_COUNTSF + t];
    out[OFF_NCS + t] = c;
    sred[t] = c;
    __syncthreads();
    for (int s = 256; s; s >>= 1) {
        if (t < s) sred[t] += sred[t + s];
        __syncthreads();
    }
    float n = sred[0];
    float csv = (c + 1e-5f) / (n + NE * 1e-5f) * n;
    for (int i = t; i < 32768; i += 512) {               // i & 511 == t, d = i>>9
        float nea = 0.99f * eavg_in[i] + 0.01f * wsf[WS_ESUM + t * DIM + (i >> 9)];
        out[OFF_NEA + i]  = nea;
        out[OFF_NEMB + i] = nea / csv;
    }
    if (t == 0) out[OFF_LOSS] = wsf[WS_LOSS] * (1.25f / 8388608.0f);
}

// ---------------------------------------------------------------------------
extern "C" void kernel_launch(void* const* d_in, const int* in_sizes, int n_in,
                              void* d_out, int out_size, void* d_ws, size_t ws_size,
                              hipStream_t stream) {
    const float* in    = (const float*)d_in[0];
    const float* embed = (const float*)d_in[1];
    const float* cs    = (const float*)d_in[2];
    const float* eavg  = (const float*)d_in[3];
    float* out = (float*)d_out;
    float* wsf = (float*)d_ws;
    int*   wsi = (int*)d_ws;

    k_init   <<<386, 256, 0, stream>>>(embed, wsf, wsi);
    k_argmin <<<256, 1024, 135232, stream>>>(in, wsf, wsi, out + OFF_INDS, out + OFF_Q);
    k_scan1  <<<NE, 256, 0, stream>>>(wsi, wsf);
    k_scan2  <<<1, 512, 0, stream>>>(wsi);
    k_scatter<<<256, 512, 0, stream>>>(wsi);
    k_sum    <<<1024, 256, 0, stream>>>(in, wsi, wsf);
    k_final  <<<1, 512, 0, stream>>>(wsf, cs, eavg, out);
}